// Round 1
// baseline (7431.104 us; speedup 1.0000x reference)
//
#include <hip/hip_runtime.h>
#include <math.h>

#define NPTS 8192
#define NPOINT 1024
#define NSAMPLE 32

typedef float v2f __attribute__((ext_vector_type(2)));

// ---------------------------------------------------------------------------
// DPP reduce steps. bound_ctrl=true: invalid-source lanes read 0, which is
// the identity for both f32-max over values >=0 and u32-max.
// ---------------------------------------------------------------------------
template <int CTRL>
__device__ __forceinline__ float dpp_fmax_step(float v) {
  int s = __builtin_amdgcn_update_dpp(0, __float_as_int(v), CTRL, 0xF, 0xF, true);
  return fmaxf(v, __int_as_float(s));
}
template <int CTRL>
__device__ __forceinline__ unsigned dpp_umax_step(unsigned v) {
  int s = __builtin_amdgcn_update_dpp(0, (int)v, CTRL, 0xF, 0xF, true);
  unsigned u = (unsigned)s;
  return (u > v) ? u : v;
}

// ---------------------------------------------------------------------------
// FPS v7: one block per batch, 256 threads, 32 points/thread as 16 float2
// pairs. v6 was still latency-bound (~2500 cyc/iter vs ~900 cyc issue floor),
// so v7 removes the remaining serial-chain memory ops:
//  (a) log-depth argmax: pair-select fused into the min loop + 4-level tree
//      (static indices -> cndmask, ~40 cyc) replaces the 32-step sequential
//      bv-update chain (~250 cyc). Right child wins only on strict >, which
//      composes to first-occurrence (min index) — bit-exact vs np.argmax.
//  (b) the wave-winner lane selects its best point's coords from its OWN
//      registers (4-level v2f cndmask tree by bI, off the DPP chain) and
//      writes {key, xyz} to LDS. Post-barrier the centroid is recovered by
//      broadcast ds_reads + 2 select levels — the per-iteration
//      readfirstlane -> s_load_dwordx4 global fetch (~200-900 cyc L2/HBM
//      latency + lgkm drain) is gone.
//  (c) centroids accumulate in LDS (cents[1024], 16KB) and are dumped
//      coalesced once at the end: the loop has NO global memory ops, so the
//      pre-barrier vmcnt drain is free.
// Bit-exact selection vs numpy: contract off, ((dx*dx+dy*dy)+dz*dz),
// min-accumulate, argmax first-occurrence, ties across lanes/waves resolved
// by max(8191-n) = min global index (n unique per lane => keys distinct).
// ---------------------------------------------------------------------------
__global__ __launch_bounds__(256, 1) void fps_kernel(const float4* __restrict__ xyz4,
                                                     float* __restrict__ new_xyz) {
#pragma clang fp contract(off)
  const int b = blockIdx.x;
  const int tid = threadIdx.x;
  const float4* xp4 = xyz4 + (size_t)b * NPTS;
  // pair j holds i=2j (.x, n=tid+512j) and i=2j+1 (.y, n=tid+512j+256)
  v2f px2[16], py2[16], pz2[16], d2[16];
#pragma unroll
  for (int j = 0; j < 16; ++j) {
    int n0 = tid + 512 * j;
    float4 a = xp4[n0];
    float4 c2 = xp4[n0 + 256];
    px2[j] = (v2f){a.x, c2.x};
    py2[j] = (v2f){a.y, c2.y};
    pz2[j] = (v2f){a.z, c2.z};
    d2[j] = (v2f){1e10f, 1e10f};        // same f32 value as np.full(1e10)
  }
  __shared__ unsigned long long rkey[2][4];  // parity double-buffered keys
  __shared__ float4 rcand[2][4];             // per-wave winner coords
  __shared__ float4 cents[NPOINT];           // centroid staging (16 KB)
  const int wv = tid >> 6;
  float4 c0 = xp4[0];                   // first centroid is point 0
  float cx = c0.x, cy = c0.y, cz = c0.z;
  if (tid == 0) cents[0] = make_float4(cx, cy, cz, 0.f);
  for (int s = 1; s < NPOINT; ++s) {
    const int par = s & 1;
    const v2f cxx = (v2f){cx, cx};
    const v2f cyy = (v2f){cy, cy};
    const v2f czz = (v2f){cz, cz};
    float pv[16];
    int pi[16];
#pragma unroll
    for (int j = 0; j < 16; ++j) {
      v2f dx = px2[j] - cxx;            // v_pk_add_f32
      v2f dy = py2[j] - cyy;
      v2f dz = pz2[j] - czz;
      v2f xx = dx * dx;                 // v_pk_mul_f32
      v2f yy = dy * dy;
      v2f zz = dz * dz;
      v2f d = (xx + yy) + zz;           // contract off: exact np order
      float dmx = fminf(d2[j].x, d.x);  // no pk_min_f32 on CDNA: scalar
      float dmy = fminf(d2[j].y, d.y);
      d2[j].x = dmx;
      d2[j].y = dmy;
      bool c = dmy > dmx;               // strict >: ties keep lower i
      pv[j] = c ? dmy : dmx;
      pi[j] = c ? (2 * j + 1) : (2 * j);
    }
    // log-depth argmax tree; all indices compile-time (stays in registers)
#pragma unroll
    for (int st = 1; st < 16; st <<= 1) {
#pragma unroll
      for (int t0 = 0; t0 < 16; t0 += (st << 1)) {
        bool c = pv[t0 + st] > pv[t0];  // right wins only on strict >
        pv[t0] = c ? pv[t0 + st] : pv[t0];
        pi[t0] = c ? pi[t0 + st] : pi[t0];
      }
    }
    const float bv = pv[0];
    const int bI = pi[0];
    const int bi = tid + (bI << 8);     // global point index (n = tid + 256*i)
    // this lane's best coords via 4-level v2f select + component pick.
    // pair p = bI>>1, so level bits are bI&2, bI&4, bI&8, bI&16.
    float bx, by, bz;
    {
      const bool l0 = (bI & 2) != 0;
      const bool l1 = (bI & 4) != 0;
      const bool l2 = (bI & 8) != 0;
      const bool l3 = (bI & 16) != 0;
      v2f ax[8], ay[8], az[8];
#pragma unroll
      for (int t = 0; t < 8; ++t) {
        ax[t] = l0 ? px2[2 * t + 1] : px2[2 * t];
        ay[t] = l0 ? py2[2 * t + 1] : py2[2 * t];
        az[t] = l0 ? pz2[2 * t + 1] : pz2[2 * t];
      }
      v2f bx4[4], by4[4], bz4[4];
#pragma unroll
      for (int t = 0; t < 4; ++t) {
        bx4[t] = l1 ? ax[2 * t + 1] : ax[2 * t];
        by4[t] = l1 ? ay[2 * t + 1] : ay[2 * t];
        bz4[t] = l1 ? az[2 * t + 1] : az[2 * t];
      }
      v2f cx2[2], cy2[2], cz2[2];
#pragma unroll
      for (int t = 0; t < 2; ++t) {
        cx2[t] = l2 ? bx4[2 * t + 1] : bx4[2 * t];
        cy2[t] = l2 ? by4[2 * t + 1] : by4[2 * t];
        cz2[t] = l2 ? bz4[2 * t + 1] : bz4[2 * t];
      }
      v2f fx = l3 ? cx2[1] : cx2[0];
      v2f fy = l3 ? cy2[1] : cy2[0];
      v2f fz = l3 ? cz2[1] : cz2[0];
      const bool lo = (bI & 1) != 0;
      bx = lo ? fx.y : fx.x;
      by = lo ? fy.y : fy.x;
      bz = lo ? fz.y : fz.x;
    }
    // --- wave reduce, phase 1: max value (bv >= 0, f32 max) ---
    float m = bv;
    m = dpp_fmax_step<0x111>(m);        // row_shr:1
    m = dpp_fmax_step<0x112>(m);        // row_shr:2
    m = dpp_fmax_step<0x114>(m);        // row_shr:4
    m = dpp_fmax_step<0x118>(m);        // row_shr:8
    m = dpp_fmax_step<0x142>(m);        // row_bcast:15
    m = dpp_fmax_step<0x143>(m);        // row_bcast:31
    float Mw = __int_as_float(__builtin_amdgcn_readlane(__float_as_int(m), 63));
    // --- phase 2: among lanes at the max, min index via max(8191-bi) ---
    unsigned kc = (bv == Mw) ? (unsigned)(8191 - bi) : 0u;
    kc = dpp_umax_step<0x111>(kc);
    kc = dpp_umax_step<0x112>(kc);
    kc = dpp_umax_step<0x114>(kc);
    kc = dpp_umax_step<0x118>(kc);
    kc = dpp_umax_step<0x142>(kc);
    kc = dpp_umax_step<0x143>(kc);
    unsigned K2 = (unsigned)__builtin_amdgcn_readlane((int)kc, 63);
    unsigned long long wkey =
        ((unsigned long long)__float_as_uint(Mw) << 32) | K2;
    // exactly one lane per wave matches (n unique across the block)
    if (bv == Mw && (unsigned)(8191 - bi) == K2) {
      rkey[par][wv] = wkey;
      rcand[par][wv] = make_float4(bx, by, bz, 0.f);
    }
    __syncthreads();                    // the only barrier per iteration
    unsigned long long kk0 = rkey[par][0];
    unsigned long long kk1 = rkey[par][1];
    unsigned long long kk2 = rkey[par][2];
    unsigned long long kk3 = rkey[par][3];
    float4 q0 = rcand[par][0];          // broadcast ds_reads, one lgkm window
    float4 q1 = rcand[par][1];
    float4 q2 = rcand[par][2];
    float4 q3 = rcand[par][3];
    bool c01 = kk1 > kk0;               // keys strictly distinct: no tie case
    bool c23 = kk3 > kk2;
    unsigned long long ka = c01 ? kk1 : kk0;
    unsigned long long kb = c23 ? kk3 : kk2;
    bool cab = kb > ka;
    float sxa = c01 ? q1.x : q0.x;
    float sya = c01 ? q1.y : q0.y;
    float sza = c01 ? q1.z : q0.z;
    float sxb = c23 ? q3.x : q2.x;
    float syb = c23 ? q3.y : q2.y;
    float szb = c23 ? q3.z : q2.z;
    cx = cab ? sxb : sxa;
    cy = cab ? syb : sya;
    cz = cab ? szb : sza;
    if (tid == 0) cents[s] = make_float4(cx, cy, cz, 0.f);
  }
  __syncthreads();
  // coalesced one-shot dump of the 1024 centroids (12 KB)
  float* outp = new_xyz + (size_t)b * NPOINT * 3;
  for (int t = tid; t < 3 * NPOINT; t += 256) {
    int sI = t / 3;
    int cI = t - 3 * sI;
    const float* cf = (const float*)&cents[sI];
    outp[t] = cf[cI];
  }
}

// ---------------------------------------------------------------------------
// Ball query: one wave per center. Replicates the reference's expanded
// sq = |a|^2 + |b|^2 - 2 a.b (contract off) and first-32-by-index semantics.
// ---------------------------------------------------------------------------
__global__ __launch_bounds__(256) void bq_kernel(const float* __restrict__ xyz,
                                                 const float* __restrict__ new_xyz,
                                                 int* __restrict__ idx_out) {
#pragma clang fp contract(off)
  __shared__ int slots[4][NSAMPLE];
  const int tid = threadIdx.x;
  const int wv = tid >> 6, lane = tid & 63;
  const int gc = blockIdx.x * 4 + wv;   // global center 0..4095
  const int b = gc >> 10;
  const float* xp = xyz + (size_t)b * 3 * NPTS;
  const float* cp = new_xyz + (size_t)gc * 3;
  const float cx = cp[0], cy = cp[1], cz = cp[2];
  const float asq = (cx * cx + cy * cy) + cz * cz;
  int cnt = 0;
  for (int base = 0; base < NPTS; base += 64) {
    int n = base + lane;
    float x = xp[n], y = xp[NPTS + n], z = xp[2 * NPTS + n];
    float bsq = (x * x + y * y) + z * z;
    float ab = (x * cx + y * cy) + z * cz;
    float sq = (asq + bsq) - 2.0f * ab;
    bool inc = !(sq > 0.01f);           // same f32 threshold as reference
    unsigned long long mk = __ballot(inc);
    int pos = cnt + (int)__popcll(mk & ((1ull << lane) - 1ull));
    if (inc && pos < NSAMPLE) slots[wv][pos] = n;
    cnt += (int)__popcll(mk);
    if (cnt >= NSAMPLE) break;          // wave-uniform
  }
  __syncthreads();
  if (lane < NSAMPLE) {
    int first = slots[wv][0];           // >=1 hit guaranteed (center itself)
    int v = (lane < cnt) ? slots[wv][lane] : first;
    idx_out[(size_t)gc * NSAMPLE + lane] = v;
  }
}

// ---------------------------------------------------------------------------
// Setup (grid = 128 blocks): every block packs 256 points of the float4
// coord table xyz4[b][n] = (x,y,z,0); block 0 additionally transposes
// w3 -> w3t and folds BN (+bias) into per-channel scale/shift.
// ---------------------------------------------------------------------------
__global__ __launch_bounds__(256) void setup_kernel(
    const float* __restrict__ xyz, const float* __restrict__ w3,
    const float* __restrict__ b1, const float* __restrict__ g1, const float* __restrict__ t1,
    const float* __restrict__ m1, const float* __restrict__ v1,
    const float* __restrict__ b2, const float* __restrict__ g2, const float* __restrict__ t2,
    const float* __restrict__ m2, const float* __restrict__ v2,
    const float* __restrict__ b3, const float* __restrict__ g3, const float* __restrict__ t3,
    const float* __restrict__ m3, const float* __restrict__ v3,
    float4* __restrict__ xyz4, float* __restrict__ w3t, float* __restrict__ scsh) {
  int tid = threadIdx.x;
  int p = blockIdx.x * 256 + tid;       // 0..32767
  int bb = p >> 13, n = p & 8191;
  const float* src = xyz + (size_t)bb * 3 * NPTS;
  xyz4[p] = make_float4(src[n], src[NPTS + n], src[2 * NPTS + n], 0.f);
  if (blockIdx.x != 0) return;
  for (int i = tid; i < 8192; i += 256) {
    int o = i >> 6, c = i & 63;
    w3t[c * 128 + o] = w3[i];
  }
  if (tid < 64) {
    float s = g1[tid] / sqrtf(v1[tid] + 1e-5f);
    scsh[tid] = s;
    scsh[64 + tid] = (b1[tid] - m1[tid]) * s + t1[tid];
    float s2 = g2[tid] / sqrtf(v2[tid] + 1e-5f);
    scsh[128 + tid] = s2;
    scsh[192 + tid] = (b2[tid] - m2[tid]) * s2 + t2[tid];
  }
  if (tid < 128) {
    float s3 = g3[tid] / sqrtf(v3[tid] + 1e-5f);
    scsh[256 + tid] = s3;
    scsh[384 + tid] = (b3[tid] - m3[tid]) * s3 + t3[tid];
  }
}

// ---------------------------------------------------------------------------
// Fused gather + MLP(6->64->64->128, BN+ReLU) + max over 32 samples.
// Block = 256 threads = 8 centers x 32 samples. Activations live in one
// 64KB LDS buffer, XOR-swizzled at float4 granularity (conflict-free at the
// b128 bank floor). L1/L2 use (center,sample) mapping (own-row, no barrier);
// L3 uses (center,channel-lane) mapping so the k-loop folds into a register
// max (no cross-lane butterfly).
// ---------------------------------------------------------------------------
__global__ __launch_bounds__(256, 2) void mlp_kernel(
    const float* __restrict__ xyz, const float* __restrict__ points,
    const float* __restrict__ new_xyz, const int* __restrict__ idx,
    const float* __restrict__ w1, const float* __restrict__ w2,
    const float* __restrict__ w3t, const float* __restrict__ scsh,
    float* __restrict__ out) {
  __shared__ float act[256 * 64];       // exactly 64 KB -> 2 blocks/CU
  float4* act4 = (float4*)act;
  const int tid = threadIdx.x;
  const int s0 = blockIdx.x * 8;
  const int b = s0 >> 10;               // 8 | 1024 -> uniform per block
  const int g = tid >> 5;               // center within block
  const int k = tid & 31;               // sample (phase A) / channel lane (L3)
  const int gc = s0 + g;
  const float* xp = xyz + (size_t)b * 3 * NPTS;
  const float* pp = points + (size_t)b * 3 * NPTS;
  const float* cp = new_xyz + (size_t)gc * 3;
  const int n = idx[(size_t)gc * NSAMPLE + k];
  float f0 = xp[n] - cp[0];
  float f1 = xp[NPTS + n] - cp[1];
  float f2 = xp[2 * NPTS + n] - cp[2];
  float f3 = pp[n];
  float f4 = pp[NPTS + n];
  float f5 = pp[2 * NPTS + n];
  const float* sc1 = scsh;        const float* sh1 = scsh + 64;
  const float* sc2 = scsh + 128;  const float* sh2 = scsh + 192;
  const float* sc3 = scsh + 256;  const float* sh3 = scsh + 384;
  const int row = tid;

  // ---- L1: x1[o] = relu(bn(W1 @ f)) -> LDS (own row, swizzled float4) ----
#pragma unroll
  for (int oc = 0; oc < 16; ++oc) {
    float va[4];
#pragma unroll
    for (int jj = 0; jj < 4; ++jj) {
      int o = oc * 4 + jj;
      const float* wr = w1 + o * 6;     // wave-uniform -> scalar loads
      float a = f0 * wr[0] + f1 * wr[1] + f2 * wr[2] +
                f3 * wr[3] + f4 * wr[4] + f5 * wr[5];
      va[jj] = fmaxf(a * sc1[o] + sh1[o], 0.f);
    }
    act4[row * 16 + (oc ^ (row & 15))] = make_float4(va[0], va[1], va[2], va[3]);
  }

  // ---- L2: own-row contraction, 64 accumulators, uniform scalar weights ----
  float acc[64];
#pragma unroll
  for (int o = 0; o < 64; ++o) acc[o] = 0.f;
  for (int cc = 0; cc < 16; ++cc) {     // dynamic: LDS handles dynamic index
    float4 av = act4[row * 16 + (cc ^ (row & 15))];
#pragma unroll
    for (int o = 0; o < 64; ++o) {
      const float* wr = w2 + o * 64 + cc * 4;  // wave-uniform address
      acc[o] += av.x * wr[0] + av.y * wr[1] + av.z * wr[2] + av.w * wr[3];
    }
  }
  // bn+relu, overwrite own row with x2 (no cross-thread x1 readers)
#pragma unroll
  for (int oc = 0; oc < 16; ++oc) {
    float va[4];
#pragma unroll
    for (int jj = 0; jj < 4; ++jj) {
      int o = oc * 4 + jj;
      va[jj] = fmaxf(acc[o] * sc2[o] + sh2[o], 0.f);
    }
    act4[row * 16 + (oc ^ (row & 15))] = make_float4(va[0], va[1], va[2], va[3]);
  }
  __syncthreads();                      // x2 visible to whole block

  // ---- L3 + max over k: lane j owns channel o3 = p*32+j ----
  const int j = k;
  const int sb = gc & 1023;
  for (int p = 0; p < 4; ++p) {
    int o3 = p * 32 + j;
    float wreg[64];
#pragma unroll
    for (int c = 0; c < 64; ++c) wreg[c] = w3t[c * 128 + o3];  // coalesced
    float osc = sc3[o3], osh = sh3[o3];
    float vmax = 0.f;                   // post-relu values are >= 0
    for (int kk = 0; kk < 32; ++kk) {
      int r2 = g * 32 + kk;             // uniform within 32-lane group
      float a0 = 0.f, a1 = 0.f, a2 = 0.f, a3 = 0.f;
#pragma unroll
      for (int cc = 0; cc < 16; cc += 4) {
        float4 u0 = act4[r2 * 16 + ((cc + 0) ^ (r2 & 15))];  // broadcast b128
        float4 u1 = act4[r2 * 16 + ((cc + 1) ^ (r2 & 15))];
        float4 u2 = act4[r2 * 16 + ((cc + 2) ^ (r2 & 15))];
        float4 u3 = act4[r2 * 16 + ((cc + 3) ^ (r2 & 15))];
        a0 += u0.x * wreg[4*cc+0]  + u0.y * wreg[4*cc+1]  + u0.z * wreg[4*cc+2]  + u0.w * wreg[4*cc+3];
        a1 += u1.x * wreg[4*cc+4]  + u1.y * wreg[4*cc+5]  + u1.z * wreg[4*cc+6]  + u1.w * wreg[4*cc+7];
        a2 += u2.x * wreg[4*cc+8]  + u2.y * wreg[4*cc+9]  + u2.z * wreg[4*cc+10] + u2.w * wreg[4*cc+11];
        a3 += u3.x * wreg[4*cc+12] + u3.y * wreg[4*cc+13] + u3.z * wreg[4*cc+14] + u3.w * wreg[4*cc+15];
      }
      float x3 = (a0 + a1) + (a2 + a3);
      vmax = fmaxf(vmax, fmaxf(x3 * osc + osh, 0.f));
    }
    out[((size_t)b * 128 + o3) * 1024 + sb] = vmax;   // (B,128,1024)
  }
}

// ---------------------------------------------------------------------------
extern "C" void kernel_launch(void* const* d_in, const int* in_sizes, int n_in,
                              void* d_out, int out_size, void* d_ws, size_t ws_size,
                              hipStream_t stream) {
  (void)in_sizes; (void)n_in; (void)out_size; (void)ws_size;
  const float* xyz    = (const float*)d_in[0];
  const float* points = (const float*)d_in[1];
  const float* w1 = (const float*)d_in[2];
  const float* b1 = (const float*)d_in[3];
  const float* g1 = (const float*)d_in[4];
  const float* t1 = (const float*)d_in[5];
  const float* m1 = (const float*)d_in[6];
  const float* v1 = (const float*)d_in[7];
  const float* w2 = (const float*)d_in[8];
  const float* b2 = (const float*)d_in[9];
  const float* g2 = (const float*)d_in[10];
  const float* t2 = (const float*)d_in[11];
  const float* m2 = (const float*)d_in[12];
  const float* v2 = (const float*)d_in[13];
  const float* w3 = (const float*)d_in[14];
  const float* b3 = (const float*)d_in[15];
  const float* g3 = (const float*)d_in[16];
  const float* t3 = (const float*)d_in[17];
  const float* m3 = (const float*)d_in[18];
  const float* v3 = (const float*)d_in[19];

  float* wsf = (float*)d_ws;
  float* new_xyz = wsf;                         // 4*1024*3   = 12288 f
  int*   idx     = (int*)(wsf + 12288);         // 4*1024*32  = 131072 i
  float* w3t     = wsf + 12288 + 131072;        // 64*128     = 8192 f
  float* scsh    = w3t + 8192;                  // 512 f
  float4* xyz4   = (float4*)(scsh + 512);       // 4*8192 float4 = 512 KB
  float* out     = (float*)d_out;               // (4,128,1024) f32

  hipLaunchKernelGGL(setup_kernel, dim3(128), dim3(256), 0, stream,
                     xyz, w3, b1, g1, t1, m1, v1, b2, g2, t2, m2, v2,
                     b3, g3, t3, m3, v3, xyz4, w3t, scsh);
  hipLaunchKernelGGL(fps_kernel, dim3(4), dim3(256), 0, stream, xyz4, new_xyz);
  hipLaunchKernelGGL(bq_kernel, dim3(1024), dim3(256), 0, stream,
                     xyz, new_xyz, idx);
  hipLaunchKernelGGL(mlp_kernel, dim3(512), dim3(256), 0, stream,
                     xyz, points, new_xyz, idx, w1, w2, w3t, scsh, out);
}

// Round 2
// 1666.318 us; speedup vs baseline: 4.4596x; 4.4596x over previous
//
#include <hip/hip_runtime.h>
#include <math.h>

#define NPTS 8192
#define NPOINT 1024
#define NSAMPLE 32

typedef float v2f __attribute__((ext_vector_type(2)));

// ---------------------------------------------------------------------------
// DPP reduce steps. bound_ctrl=true: invalid-source lanes read 0, which is
// the identity for both f32-max over values >=0 and u32-max.
// ---------------------------------------------------------------------------
template <int CTRL>
__device__ __forceinline__ float dpp_fmax_step(float v) {
  int s = __builtin_amdgcn_update_dpp(0, __float_as_int(v), CTRL, 0xF, 0xF, true);
  return fmaxf(v, __int_as_float(s));
}
template <int CTRL>
__device__ __forceinline__ unsigned dpp_umax_step(unsigned v) {
  int s = __builtin_amdgcn_update_dpp(0, (int)v, CTRL, 0xF, 0xF, true);
  unsigned u = (unsigned)s;
  return (u > v) ? u : v;
}

// ---------------------------------------------------------------------------
// FPS v8. v7 post-mortem: VGPR_Count=104 < the 128 regs the point arrays
// need => the allocator demoted them to scratch; fps went 1.05ms -> 7.2ms
// (scratch round-trips per iteration, L2-resident so invisible in
// FETCH_SIZE). v8 makes spilling impossible: 1024 threads/block, 8 points
// per thread held in 16 NAMED v2f scalars (no arrays at all). Algorithm is
// v7's (harness-verified): fused pair-select + 2-level tree argmax
// (first-occurrence exact), two-phase DPP wave reduce, winner lane carries
// its coords to LDS, cross-wave 15-compare u64 tree, winner wave recovered
// arithmetically from the key (tid = bi & 1023 => wave = (bi>>6)&15), one
// broadcast ds_read for the centroid. Zero global-memory ops in the loop;
// one barrier per iteration; centroids staged in LDS, dumped once.
// Bit-exact selection vs numpy: contract off, ((dx*dx+dy*dy)+dz*dz),
// min-accumulate, argmax first-occurrence (strict-> right wins composes to
// min index; cross-lane/wave ties via max(8191-bi) = min global index,
// keys distinct because bi is unique per lane).
// ---------------------------------------------------------------------------
__global__ __launch_bounds__(1024, 1) void fps_kernel(const float4* __restrict__ xyz4,
                                                      float* __restrict__ new_xyz) {
#pragma clang fp contract(off)
  const int b = blockIdx.x;
  const int tid = threadIdx.x;          // 0..1023
  const float4* xp4 = xyz4 + (size_t)b * NPTS;
  // pair J holds i=2J (.x, n=tid+2048J) and i=2J+1 (.y, n=tid+2048J+1024)
  v2f px0, py0, pz0, dd0;
  v2f px1, py1, pz1, dd1;
  v2f px2, py2, pz2, dd2;
  v2f px3, py3, pz3, dd3;
#define FPS_LOAD(J, PX, PY, PZ, PD)            \
  {                                            \
    float4 a = xp4[tid + 2048 * J];            \
    float4 c2 = xp4[tid + 2048 * J + 1024];    \
    PX = (v2f){a.x, c2.x};                     \
    PY = (v2f){a.y, c2.y};                     \
    PZ = (v2f){a.z, c2.z};                     \
    PD = (v2f){1e10f, 1e10f};                  \
  }
  FPS_LOAD(0, px0, py0, pz0, dd0)
  FPS_LOAD(1, px1, py1, pz1, dd1)
  FPS_LOAD(2, px2, py2, pz2, dd2)
  FPS_LOAD(3, px3, py3, pz3, dd3)
  __shared__ unsigned long long rkey[2][16];   // parity double-buffered keys
  __shared__ float4 rcand[2][16];              // per-wave winner coords
  __shared__ float4 cents[NPOINT];             // centroid staging (16 KB)
  const int wv = tid >> 6;
  float4 c0 = xp4[0];                   // first centroid is point 0
  float cx = c0.x, cy = c0.y, cz = c0.z;
  if (tid == 0) cents[0] = make_float4(cx, cy, cz, 0.f);
  for (int s = 1; s < NPOINT; ++s) {
    const int par = s & 1;
    const v2f cxx = (v2f){cx, cx};
    const v2f cyy = (v2f){cy, cy};
    const v2f czz = (v2f){cz, cz};
    float v0, v1, v2, v3;
    int i0, i1, i2, i3;
#define FPS_DIST(J, PX, PY, PZ, PD, PV, PI)    \
  {                                            \
    v2f dx = PX - cxx;                         \
    v2f dy = PY - cyy;                         \
    v2f dz = PZ - czz;                         \
    v2f xx = dx * dx;                          \
    v2f yy = dy * dy;                          \
    v2f zz = dz * dz;                          \
    v2f d = (xx + yy) + zz;                    \
    float dmx = fminf(PD.x, d.x);              \
    float dmy = fminf(PD.y, d.y);              \
    PD.x = dmx;                                \
    PD.y = dmy;                                \
    bool c = dmy > dmx;                        \
    PV = c ? dmy : dmx;                        \
    PI = c ? (2 * J + 1) : (2 * J);            \
  }
    FPS_DIST(0, px0, py0, pz0, dd0, v0, i0)
    FPS_DIST(1, px1, py1, pz1, dd1, v1, i1)
    FPS_DIST(2, px2, py2, pz2, dd2, v2, i2)
    FPS_DIST(3, px3, py3, pz3, dd3, v3, i3)
    // 2-level argmax tree; right child wins only on strict > (min index)
    bool c01 = v1 > v0;
    float va = c01 ? v1 : v0;
    int ia = c01 ? i1 : i0;
    bool c23 = v3 > v2;
    float vb = c23 ? v3 : v2;
    int ib = c23 ? i3 : i2;
    bool cab = vb > va;
    const float bv = cab ? vb : va;
    const int bI = cab ? ib : ia;
    const int bi = tid + (bI << 10);    // global point index (n = tid+1024*i)
    // this lane's best coords: 2-level v2f select + component pick
    // (off the DPP critical chain; tiny register cost at 4 pairs)
    v2f sx0 = (bI & 2) ? px1 : px0;
    v2f sy0 = (bI & 2) ? py1 : py0;
    v2f sz0 = (bI & 2) ? pz1 : pz0;
    v2f sx1 = (bI & 2) ? px3 : px2;
    v2f sy1 = (bI & 2) ? py3 : py2;
    v2f sz1 = (bI & 2) ? pz3 : pz2;
    v2f sx = (bI & 4) ? sx1 : sx0;
    v2f sy = (bI & 4) ? sy1 : sy0;
    v2f sz = (bI & 4) ? sz1 : sz0;
    const float bx = (bI & 1) ? sx.y : sx.x;
    const float by = (bI & 1) ? sy.y : sy.x;
    const float bz = (bI & 1) ? sz.y : sz.x;
    // --- wave reduce, phase 1: max value (bv >= 0, f32 max) ---
    float m = bv;
    m = dpp_fmax_step<0x111>(m);        // row_shr:1
    m = dpp_fmax_step<0x112>(m);        // row_shr:2
    m = dpp_fmax_step<0x114>(m);        // row_shr:4
    m = dpp_fmax_step<0x118>(m);        // row_shr:8
    m = dpp_fmax_step<0x142>(m);        // row_bcast:15
    m = dpp_fmax_step<0x143>(m);        // row_bcast:31
    float Mw = __int_as_float(__builtin_amdgcn_readlane(__float_as_int(m), 63));
    // --- phase 2: among lanes at the max, min index via max(8191-bi) ---
    unsigned kc = (bv == Mw) ? (unsigned)(8191 - bi) : 0u;
    kc = dpp_umax_step<0x111>(kc);
    kc = dpp_umax_step<0x112>(kc);
    kc = dpp_umax_step<0x114>(kc);
    kc = dpp_umax_step<0x118>(kc);
    kc = dpp_umax_step<0x142>(kc);
    kc = dpp_umax_step<0x143>(kc);
    unsigned K2 = (unsigned)__builtin_amdgcn_readlane((int)kc, 63);
    unsigned long long wkey =
        ((unsigned long long)__float_as_uint(Mw) << 32) | K2;
    // exactly one lane per wave matches (bi unique across the block)
    if (bv == Mw && (unsigned)(8191 - bi) == K2) {
      rkey[par][wv] = wkey;
      rcand[par][wv] = make_float4(bx, by, bz, 0.f);
    }
    __syncthreads();                    // the only barrier per iteration
    // --- cross-wave reduce: 15-compare u64 tree over 16 keys ---
    const unsigned long long* rk = rkey[par];
    unsigned long long kA0 = rk[0], kA1 = rk[1], kA2 = rk[2], kA3 = rk[3];
    unsigned long long kA4 = rk[4], kA5 = rk[5], kA6 = rk[6], kA7 = rk[7];
    unsigned long long kA8 = rk[8], kA9 = rk[9], kAa = rk[10], kAb = rk[11];
    unsigned long long kAc = rk[12], kAd = rk[13], kAe = rk[14], kAf = rk[15];
#define FPS_MAX2(A, B) (((B) > (A)) ? (B) : (A))
    unsigned long long m0 = FPS_MAX2(kA0, kA1);
    unsigned long long m1 = FPS_MAX2(kA2, kA3);
    unsigned long long m2 = FPS_MAX2(kA4, kA5);
    unsigned long long m3 = FPS_MAX2(kA6, kA7);
    unsigned long long m4 = FPS_MAX2(kA8, kA9);
    unsigned long long m5 = FPS_MAX2(kAa, kAb);
    unsigned long long m6 = FPS_MAX2(kAc, kAd);
    unsigned long long m7 = FPS_MAX2(kAe, kAf);
    unsigned long long n0 = FPS_MAX2(m0, m1);
    unsigned long long n1 = FPS_MAX2(m2, m3);
    unsigned long long n2 = FPS_MAX2(m4, m5);
    unsigned long long n3 = FPS_MAX2(m6, m7);
    unsigned long long q0 = FPS_MAX2(n0, n1);
    unsigned long long q1 = FPS_MAX2(n2, n3);
    unsigned long long km = FPS_MAX2(q0, q1);
    const int gi = 8191 - (int)(unsigned)(km & 0xFFFFFFFFull);
    // winner thread tid = gi & 1023 => its wave = (gi >> 6) & 15
    const int wstar = (gi >> 6) & 15;
    float4 cc = rcand[par][wstar];      // broadcast ds_read
    cx = cc.x;
    cy = cc.y;
    cz = cc.z;
    if (tid == 0) cents[s] = make_float4(cx, cy, cz, 0.f);
  }
  __syncthreads();
  // coalesced one-shot dump of the 1024 centroids (12 KB)
  float* outp = new_xyz + (size_t)b * NPOINT * 3;
  for (int t = tid; t < 3 * NPOINT; t += 1024) {
    int sI = t / 3;
    int cI = t - 3 * sI;
    const float* cf = (const float*)&cents[sI];
    outp[t] = cf[cI];
  }
}

// ---------------------------------------------------------------------------
// Ball query: one wave per center. Replicates the reference's expanded
// sq = |a|^2 + |b|^2 - 2 a.b (contract off) and first-32-by-index semantics.
// ---------------------------------------------------------------------------
__global__ __launch_bounds__(256) void bq_kernel(const float* __restrict__ xyz,
                                                 const float* __restrict__ new_xyz,
                                                 int* __restrict__ idx_out) {
#pragma clang fp contract(off)
  __shared__ int slots[4][NSAMPLE];
  const int tid = threadIdx.x;
  const int wv = tid >> 6, lane = tid & 63;
  const int gc = blockIdx.x * 4 + wv;   // global center 0..4095
  const int b = gc >> 10;
  const float* xp = xyz + (size_t)b * 3 * NPTS;
  const float* cp = new_xyz + (size_t)gc * 3;
  const float cx = cp[0], cy = cp[1], cz = cp[2];
  const float asq = (cx * cx + cy * cy) + cz * cz;
  int cnt = 0;
  for (int base = 0; base < NPTS; base += 64) {
    int n = base + lane;
    float x = xp[n], y = xp[NPTS + n], z = xp[2 * NPTS + n];
    float bsq = (x * x + y * y) + z * z;
    float ab = (x * cx + y * cy) + z * cz;
    float sq = (asq + bsq) - 2.0f * ab;
    bool inc = !(sq > 0.01f);           // same f32 threshold as reference
    unsigned long long mk = __ballot(inc);
    int pos = cnt + (int)__popcll(mk & ((1ull << lane) - 1ull));
    if (inc && pos < NSAMPLE) slots[wv][pos] = n;
    cnt += (int)__popcll(mk);
    if (cnt >= NSAMPLE) break;          // wave-uniform
  }
  __syncthreads();
  if (lane < NSAMPLE) {
    int first = slots[wv][0];           // >=1 hit guaranteed (center itself)
    int v = (lane < cnt) ? slots[wv][lane] : first;
    idx_out[(size_t)gc * NSAMPLE + lane] = v;
  }
}

// ---------------------------------------------------------------------------
// Setup (grid = 128 blocks): every block packs 256 points of the float4
// coord table xyz4[b][n] = (x,y,z,0); block 0 additionally transposes
// w3 -> w3t and folds BN (+bias) into per-channel scale/shift.
// ---------------------------------------------------------------------------
__global__ __launch_bounds__(256) void setup_kernel(
    const float* __restrict__ xyz, const float* __restrict__ w3,
    const float* __restrict__ b1, const float* __restrict__ g1, const float* __restrict__ t1,
    const float* __restrict__ m1, const float* __restrict__ v1,
    const float* __restrict__ b2, const float* __restrict__ g2, const float* __restrict__ t2,
    const float* __restrict__ m2, const float* __restrict__ v2,
    const float* __restrict__ b3, const float* __restrict__ g3, const float* __restrict__ t3,
    const float* __restrict__ m3, const float* __restrict__ v3,
    float4* __restrict__ xyz4, float* __restrict__ w3t, float* __restrict__ scsh) {
  int tid = threadIdx.x;
  int p = blockIdx.x * 256 + tid;       // 0..32767
  int bb = p >> 13, n = p & 8191;
  const float* src = xyz + (size_t)bb * 3 * NPTS;
  xyz4[p] = make_float4(src[n], src[NPTS + n], src[2 * NPTS + n], 0.f);
  if (blockIdx.x != 0) return;
  for (int i = tid; i < 8192; i += 256) {
    int o = i >> 6, c = i & 63;
    w3t[c * 128 + o] = w3[i];
  }
  if (tid < 64) {
    float s = g1[tid] / sqrtf(v1[tid] + 1e-5f);
    scsh[tid] = s;
    scsh[64 + tid] = (b1[tid] - m1[tid]) * s + t1[tid];
    float s2 = g2[tid] / sqrtf(v2[tid] + 1e-5f);
    scsh[128 + tid] = s2;
    scsh[192 + tid] = (b2[tid] - m2[tid]) * s2 + t2[tid];
  }
  if (tid < 128) {
    float s3 = g3[tid] / sqrtf(v3[tid] + 1e-5f);
    scsh[256 + tid] = s3;
    scsh[384 + tid] = (b3[tid] - m3[tid]) * s3 + t3[tid];
  }
}

// ---------------------------------------------------------------------------
// Fused gather + MLP(6->64->64->128, BN+ReLU) + max over 32 samples.
// Block = 256 threads = 8 centers x 32 samples. Activations live in one
// 64KB LDS buffer, XOR-swizzled at float4 granularity (conflict-free at the
// b128 bank floor). L1/L2 use (center,sample) mapping (own-row, no barrier);
// L3 uses (center,channel-lane) mapping so the k-loop folds into a register
// max (no cross-lane butterfly).
// ---------------------------------------------------------------------------
__global__ __launch_bounds__(256, 2) void mlp_kernel(
    const float* __restrict__ xyz, const float* __restrict__ points,
    const float* __restrict__ new_xyz, const int* __restrict__ idx,
    const float* __restrict__ w1, const float* __restrict__ w2,
    const float* __restrict__ w3t, const float* __restrict__ scsh,
    float* __restrict__ out) {
  __shared__ float act[256 * 64];       // exactly 64 KB -> 2 blocks/CU
  float4* act4 = (float4*)act;
  const int tid = threadIdx.x;
  const int s0 = blockIdx.x * 8;
  const int b = s0 >> 10;               // 8 | 1024 -> uniform per block
  const int g = tid >> 5;               // center within block
  const int k = tid & 31;               // sample (phase A) / channel lane (L3)
  const int gc = s0 + g;
  const float* xp = xyz + (size_t)b * 3 * NPTS;
  const float* pp = points + (size_t)b * 3 * NPTS;
  const float* cp = new_xyz + (size_t)gc * 3;
  const int n = idx[(size_t)gc * NSAMPLE + k];
  float f0 = xp[n] - cp[0];
  float f1 = xp[NPTS + n] - cp[1];
  float f2 = xp[2 * NPTS + n] - cp[2];
  float f3 = pp[n];
  float f4 = pp[NPTS + n];
  float f5 = pp[2 * NPTS + n];
  const float* sc1 = scsh;        const float* sh1 = scsh + 64;
  const float* sc2 = scsh + 128;  const float* sh2 = scsh + 192;
  const float* sc3 = scsh + 256;  const float* sh3 = scsh + 384;
  const int row = tid;

  // ---- L1: x1[o] = relu(bn(W1 @ f)) -> LDS (own row, swizzled float4) ----
#pragma unroll
  for (int oc = 0; oc < 16; ++oc) {
    float va[4];
#pragma unroll
    for (int jj = 0; jj < 4; ++jj) {
      int o = oc * 4 + jj;
      const float* wr = w1 + o * 6;     // wave-uniform -> scalar loads
      float a = f0 * wr[0] + f1 * wr[1] + f2 * wr[2] +
                f3 * wr[3] + f4 * wr[4] + f5 * wr[5];
      va[jj] = fmaxf(a * sc1[o] + sh1[o], 0.f);
    }
    act4[row * 16 + (oc ^ (row & 15))] = make_float4(va[0], va[1], va[2], va[3]);
  }

  // ---- L2: own-row contraction, 64 accumulators, uniform scalar weights ----
  float acc[64];
#pragma unroll
  for (int o = 0; o < 64; ++o) acc[o] = 0.f;
  for (int cc = 0; cc < 16; ++cc) {     // dynamic: LDS handles dynamic index
    float4 av = act4[row * 16 + (cc ^ (row & 15))];
#pragma unroll
    for (int o = 0; o < 64; ++o) {
      const float* wr = w2 + o * 64 + cc * 4;  // wave-uniform address
      acc[o] += av.x * wr[0] + av.y * wr[1] + av.z * wr[2] + av.w * wr[3];
    }
  }
  // bn+relu, overwrite own row with x2 (no cross-thread x1 readers)
#pragma unroll
  for (int oc = 0; oc < 16; ++oc) {
    float va[4];
#pragma unroll
    for (int jj = 0; jj < 4; ++jj) {
      int o = oc * 4 + jj;
      va[jj] = fmaxf(acc[o] * sc2[o] + sh2[o], 0.f);
    }
    act4[row * 16 + (oc ^ (row & 15))] = make_float4(va[0], va[1], va[2], va[3]);
  }
  __syncthreads();                      // x2 visible to whole block

  // ---- L3 + max over k: lane j owns channel o3 = p*32+j ----
  const int j = k;
  const int sb = gc & 1023;
  for (int p = 0; p < 4; ++p) {
    int o3 = p * 32 + j;
    float wreg[64];
#pragma unroll
    for (int c = 0; c < 64; ++c) wreg[c] = w3t[c * 128 + o3];  // coalesced
    float osc = sc3[o3], osh = sh3[o3];
    float vmax = 0.f;                   // post-relu values are >= 0
    for (int kk = 0; kk < 32; ++kk) {
      int r2 = g * 32 + kk;             // uniform within 32-lane group
      float a0 = 0.f, a1 = 0.f, a2 = 0.f, a3 = 0.f;
#pragma unroll
      for (int cc = 0; cc < 16; cc += 4) {
        float4 u0 = act4[r2 * 16 + ((cc + 0) ^ (r2 & 15))];  // broadcast b128
        float4 u1 = act4[r2 * 16 + ((cc + 1) ^ (r2 & 15))];
        float4 u2 = act4[r2 * 16 + ((cc + 2) ^ (r2 & 15))];
        float4 u3 = act4[r2 * 16 + ((cc + 3) ^ (r2 & 15))];
        a0 += u0.x * wreg[4*cc+0]  + u0.y * wreg[4*cc+1]  + u0.z * wreg[4*cc+2]  + u0.w * wreg[4*cc+3];
        a1 += u1.x * wreg[4*cc+4]  + u1.y * wreg[4*cc+5]  + u1.z * wreg[4*cc+6]  + u1.w * wreg[4*cc+7];
        a2 += u2.x * wreg[4*cc+8]  + u2.y * wreg[4*cc+9]  + u2.z * wreg[4*cc+10] + u2.w * wreg[4*cc+11];
        a3 += u3.x * wreg[4*cc+12] + u3.y * wreg[4*cc+13] + u3.z * wreg[4*cc+14] + u3.w * wreg[4*cc+15];
      }
      float x3 = (a0 + a1) + (a2 + a3);
      vmax = fmaxf(vmax, fmaxf(x3 * osc + osh, 0.f));
    }
    out[((size_t)b * 128 + o3) * 1024 + sb] = vmax;   // (B,128,1024)
  }
}

// ---------------------------------------------------------------------------
extern "C" void kernel_launch(void* const* d_in, const int* in_sizes, int n_in,
                              void* d_out, int out_size, void* d_ws, size_t ws_size,
                              hipStream_t stream) {
  (void)in_sizes; (void)n_in; (void)out_size; (void)ws_size;
  const float* xyz    = (const float*)d_in[0];
  const float* points = (const float*)d_in[1];
  const float* w1 = (const float*)d_in[2];
  const float* b1 = (const float*)d_in[3];
  const float* g1 = (const float*)d_in[4];
  const float* t1 = (const float*)d_in[5];
  const float* m1 = (const float*)d_in[6];
  const float* v1 = (const float*)d_in[7];
  const float* w2 = (const float*)d_in[8];
  const float* b2 = (const float*)d_in[9];
  const float* g2 = (const float*)d_in[10];
  const float* t2 = (const float*)d_in[11];
  const float* m2 = (const float*)d_in[12];
  const float* v2 = (const float*)d_in[13];
  const float* w3 = (const float*)d_in[14];
  const float* b3 = (const float*)d_in[15];
  const float* g3 = (const float*)d_in[16];
  const float* t3 = (const float*)d_in[17];
  const float* m3 = (const float*)d_in[18];
  const float* v3 = (const float*)d_in[19];

  float* wsf = (float*)d_ws;
  float* new_xyz = wsf;                         // 4*1024*3   = 12288 f
  int*   idx     = (int*)(wsf + 12288);         // 4*1024*32  = 131072 i
  float* w3t     = wsf + 12288 + 131072;        // 64*128     = 8192 f
  float* scsh    = w3t + 8192;                  // 512 f
  float4* xyz4   = (float4*)(scsh + 512);       // 4*8192 float4 = 512 KB
  float* out     = (float*)d_out;               // (4,128,1024) f32

  hipLaunchKernelGGL(setup_kernel, dim3(128), dim3(256), 0, stream,
                     xyz, w3, b1, g1, t1, m1, v1, b2, g2, t2, m2, v2,
                     b3, g3, t3, m3, v3, xyz4, w3t, scsh);
  hipLaunchKernelGGL(fps_kernel, dim3(4), dim3(1024), 0, stream, xyz4, new_xyz);
  hipLaunchKernelGGL(bq_kernel, dim3(1024), dim3(256), 0, stream,
                     xyz, new_xyz, idx);
  hipLaunchKernelGGL(mlp_kernel, dim3(512), dim3(256), 0, stream,
                     xyz, points, new_xyz, idx, w1, w2, w3t, scsh, out);
}

// Round 3
// 1493.198 us; speedup vs baseline: 4.9766x; 1.1159x over previous
//
#include <hip/hip_runtime.h>
#include <math.h>

#define NPTS 8192
#define NPOINT 1024
#define NSAMPLE 32

typedef float v2f __attribute__((ext_vector_type(2)));

// ---------------------------------------------------------------------------
// DPP reduce steps. bound_ctrl=true: invalid-source lanes read 0, which is
// the identity for both f32-max over values >=0 and u32-max.
// ---------------------------------------------------------------------------
template <int CTRL>
__device__ __forceinline__ float dpp_fmax_step(float v) {
  int s = __builtin_amdgcn_update_dpp(0, __float_as_int(v), CTRL, 0xF, 0xF, true);
  return fmaxf(v, __int_as_float(s));
}
template <int CTRL>
__device__ __forceinline__ unsigned dpp_umax_step(unsigned v) {
  int s = __builtin_amdgcn_update_dpp(0, (int)v, CTRL, 0xF, 0xF, true);
  unsigned u = (unsigned)s;
  return (u > v) ? u : v;
}

// ---------------------------------------------------------------------------
// FPS v9. v8 post-mortem: issue-bound (active CUs ~85% VALUBusy); per-wave
// overhead (fat 15-compare u64 cross-wave tree, ~60 instr) was replicated
// on 4 waves/SIMD. v9: (a) 512 threads = 8 waves = 2/SIMD, 16 pts/thread in
// 8 NAMED v2f pairs (dist issue per SIMD unchanged, overhead halved);
// (b) slim lane-parallel cross-wave reduce: lane&7 reads packed {Mw,K2}
// from LDS, 3 DPP fmax + readlane(7), predicate, 3 DPP umax + readlane(7)
// (~17 instr vs ~60). Ordering semantics identical to v8 (harness-passed):
// value bits monotone for >=0, max(8191-bi) = min global index, keys
// distinct (bi unique per lane). Zero global ops in loop, one barrier/iter,
// centroids staged in LDS and dumped once.
// Bit-exact vs numpy: contract off, ((dx*dx+dy*dy)+dz*dz), min-accumulate,
// argmax first-occurrence (strict > right-wins = min index at every level).
// ---------------------------------------------------------------------------
__global__ __launch_bounds__(512, 1) void fps_kernel(const float4* __restrict__ xyz4,
                                                     float* __restrict__ new_xyz) {
#pragma clang fp contract(off)
  const int b = blockIdx.x;
  const int tid = threadIdx.x;          // 0..511
  const float4* xp4 = xyz4 + (size_t)b * NPTS;
  // pair J holds i=2J (.x, n=tid+1024J) and i=2J+1 (.y, n=tid+1024J+512)
  v2f px0, py0, pz0, dd0;
  v2f px1, py1, pz1, dd1;
  v2f px2, py2, pz2, dd2;
  v2f px3, py3, pz3, dd3;
  v2f px4, py4, pz4, dd4;
  v2f px5, py5, pz5, dd5;
  v2f px6, py6, pz6, dd6;
  v2f px7, py7, pz7, dd7;
#define FPS_LOAD(J, PX, PY, PZ, PD)            \
  {                                            \
    float4 a = xp4[tid + 1024 * J];            \
    float4 c2 = xp4[tid + 1024 * J + 512];     \
    PX = (v2f){a.x, c2.x};                     \
    PY = (v2f){a.y, c2.y};                     \
    PZ = (v2f){a.z, c2.z};                     \
    PD = (v2f){1e10f, 1e10f};                  \
  }
  FPS_LOAD(0, px0, py0, pz0, dd0)
  FPS_LOAD(1, px1, py1, pz1, dd1)
  FPS_LOAD(2, px2, py2, pz2, dd2)
  FPS_LOAD(3, px3, py3, pz3, dd3)
  FPS_LOAD(4, px4, py4, pz4, dd4)
  FPS_LOAD(5, px5, py5, pz5, dd5)
  FPS_LOAD(6, px6, py6, pz6, dd6)
  FPS_LOAD(7, px7, py7, pz7, dd7)
  __shared__ uint2 rwk[2][8];                  // per-wave {Mw bits, K2}
  __shared__ float4 rcand[2][8];               // per-wave winner coords
  __shared__ float4 cents[NPOINT];             // centroid staging (16 KB)
  const int wv = tid >> 6;
  const int lane = tid & 63;
  float4 c0 = xp4[0];                   // first centroid is point 0
  float cx = c0.x, cy = c0.y, cz = c0.z;
  if (tid == 0) cents[0] = make_float4(cx, cy, cz, 0.f);
  for (int s = 1; s < NPOINT; ++s) {
    const int par = s & 1;
    const v2f cxx = (v2f){cx, cx};
    const v2f cyy = (v2f){cy, cy};
    const v2f czz = (v2f){cz, cz};
    float v0, v1, v2, v3, v4, v5, v6, v7;
    int i0, i1, i2, i3, i4, i5, i6, i7;
#define FPS_DIST(J, PX, PY, PZ, PD, PV, PI)    \
  {                                            \
    v2f dx = PX - cxx;                         \
    v2f dy = PY - cyy;                         \
    v2f dz = PZ - czz;                         \
    v2f xx = dx * dx;                          \
    v2f yy = dy * dy;                          \
    v2f zz = dz * dz;                          \
    v2f d = (xx + yy) + zz;                    \
    float dmx = fminf(PD.x, d.x);              \
    float dmy = fminf(PD.y, d.y);              \
    PD.x = dmx;                                \
    PD.y = dmy;                                \
    bool c = dmy > dmx;                        \
    PV = c ? dmy : dmx;                        \
    PI = c ? (2 * J + 1) : (2 * J);            \
  }
    FPS_DIST(0, px0, py0, pz0, dd0, v0, i0)
    FPS_DIST(1, px1, py1, pz1, dd1, v1, i1)
    FPS_DIST(2, px2, py2, pz2, dd2, v2, i2)
    FPS_DIST(3, px3, py3, pz3, dd3, v3, i3)
    FPS_DIST(4, px4, py4, pz4, dd4, v4, i4)
    FPS_DIST(5, px5, py5, pz5, dd5, v5, i5)
    FPS_DIST(6, px6, py6, pz6, dd6, v6, i6)
    FPS_DIST(7, px7, py7, pz7, dd7, v7, i7)
    // 3-level argmax tree; right child wins only on strict > (min index)
    bool cA = v1 > v0;  float a0 = cA ? v1 : v0;  int j0 = cA ? i1 : i0;
    bool cB = v3 > v2;  float a1 = cB ? v3 : v2;  int j1 = cB ? i3 : i2;
    bool cC = v5 > v4;  float a2 = cC ? v5 : v4;  int j2 = cC ? i5 : i4;
    bool cD = v7 > v6;  float a3 = cD ? v7 : v6;  int j3 = cD ? i7 : i6;
    bool cE = a1 > a0;  float b0 = cE ? a1 : a0;  int k0 = cE ? j1 : j0;
    bool cF = a3 > a2;  float b1 = cF ? a3 : a2;  int k1 = cF ? j3 : j2;
    bool cG = b1 > b0;
    const float bv = cG ? b1 : b0;
    const int bI = cG ? k1 : k0;        // 0..15
    const int bi = tid + (bI << 9);     // global point index (n = tid+512*i)
    // this lane's best coords: 3-level v2f select + component pick
    // (off the DPP critical chain)
    v2f tx0 = (bI & 2) ? px1 : px0;
    v2f ty0 = (bI & 2) ? py1 : py0;
    v2f tz0 = (bI & 2) ? pz1 : pz0;
    v2f tx1 = (bI & 2) ? px3 : px2;
    v2f ty1 = (bI & 2) ? py3 : py2;
    v2f tz1 = (bI & 2) ? pz3 : pz2;
    v2f tx2 = (bI & 2) ? px5 : px4;
    v2f ty2 = (bI & 2) ? py5 : py4;
    v2f tz2 = (bI & 2) ? pz5 : pz4;
    v2f tx3 = (bI & 2) ? px7 : px6;
    v2f ty3 = (bI & 2) ? py7 : py6;
    v2f tz3 = (bI & 2) ? pz7 : pz6;
    v2f ux0 = (bI & 4) ? tx1 : tx0;
    v2f uy0 = (bI & 4) ? ty1 : ty0;
    v2f uz0 = (bI & 4) ? tz1 : tz0;
    v2f ux1 = (bI & 4) ? tx3 : tx2;
    v2f uy1 = (bI & 4) ? ty3 : ty2;
    v2f uz1 = (bI & 4) ? tz3 : tz2;
    v2f fx = (bI & 8) ? ux1 : ux0;
    v2f fy = (bI & 8) ? uy1 : uy0;
    v2f fz = (bI & 8) ? uz1 : uz0;
    const float bx = (bI & 1) ? fx.y : fx.x;
    const float by = (bI & 1) ? fy.y : fy.x;
    const float bz = (bI & 1) ? fz.y : fz.x;
    // --- wave reduce, phase 1: max value (bv >= 0, f32 max) ---
    float m = bv;
    m = dpp_fmax_step<0x111>(m);        // row_shr:1
    m = dpp_fmax_step<0x112>(m);        // row_shr:2
    m = dpp_fmax_step<0x114>(m);        // row_shr:4
    m = dpp_fmax_step<0x118>(m);        // row_shr:8
    m = dpp_fmax_step<0x142>(m);        // row_bcast:15
    m = dpp_fmax_step<0x143>(m);        // row_bcast:31
    float Mw = __int_as_float(__builtin_amdgcn_readlane(__float_as_int(m), 63));
    // --- phase 2: among lanes at the max, min index via max(8191-bi) ---
    unsigned kc = (bv == Mw) ? (unsigned)(8191 - bi) : 0u;
    kc = dpp_umax_step<0x111>(kc);
    kc = dpp_umax_step<0x112>(kc);
    kc = dpp_umax_step<0x114>(kc);
    kc = dpp_umax_step<0x118>(kc);
    kc = dpp_umax_step<0x142>(kc);
    kc = dpp_umax_step<0x143>(kc);
    unsigned K2 = (unsigned)__builtin_amdgcn_readlane((int)kc, 63);
    // exactly one lane per wave matches (bi unique across the block)
    if (bv == Mw && (unsigned)(8191 - bi) == K2) {
      rwk[par][wv] = make_uint2(__float_as_uint(Mw), K2);
      rcand[par][wv] = make_float4(bx, by, bz, 0.f);
    }
    __syncthreads();                    // the only barrier per iteration
    // --- slim cross-wave reduce: lane-parallel over the 8 wave results ---
    uint2 wk = rwk[par][lane & 7];      // 8-way broadcast ds_read_b64
    float mw = __uint_as_float(wk.x);
    float mm = mw;
    mm = dpp_fmax_step<0x111>(mm);      // row_shr:1 (within row of 16)
    mm = dpp_fmax_step<0x112>(mm);      // row_shr:2
    mm = dpp_fmax_step<0x114>(mm);      // row_shr:4 -> lane 7 = max(l0..l7)
    float Mv = __int_as_float(__builtin_amdgcn_readlane(__float_as_int(mm), 7));
    unsigned kx = (mw == Mv) ? wk.y : 0u;
    kx = dpp_umax_step<0x111>(kx);
    kx = dpp_umax_step<0x112>(kx);
    kx = dpp_umax_step<0x114>(kx);
    unsigned K = (unsigned)__builtin_amdgcn_readlane((int)kx, 7);
    const int gi = 8191 - (int)K;
    // winner thread tid = gi & 511 => its wave = (gi >> 6) & 7
    const int wstar = (gi >> 6) & 7;
    float4 cc = rcand[par][wstar];      // broadcast ds_read_b128
    cx = cc.x;
    cy = cc.y;
    cz = cc.z;
    if (tid == 0) cents[s] = make_float4(cx, cy, cz, 0.f);
  }
  __syncthreads();
  // coalesced one-shot dump of the 1024 centroids (12 KB)
  float* outp = new_xyz + (size_t)b * NPOINT * 3;
  for (int t = tid; t < 3 * NPOINT; t += 512) {
    int sI = t / 3;
    int cI = t - 3 * sI;
    const float* cf = (const float*)&cents[sI];
    outp[t] = cf[cI];
  }
}

// ---------------------------------------------------------------------------
// Ball query: one wave per center. Replicates the reference's expanded
// sq = |a|^2 + |b|^2 - 2 a.b (contract off) and first-32-by-index semantics.
// ---------------------------------------------------------------------------
__global__ __launch_bounds__(256) void bq_kernel(const float* __restrict__ xyz,
                                                 const float* __restrict__ new_xyz,
                                                 int* __restrict__ idx_out) {
#pragma clang fp contract(off)
  __shared__ int slots[4][NSAMPLE];
  const int tid = threadIdx.x;
  const int wv = tid >> 6, lane = tid & 63;
  const int gc = blockIdx.x * 4 + wv;   // global center 0..4095
  const int b = gc >> 10;
  const float* xp = xyz + (size_t)b * 3 * NPTS;
  const float* cp = new_xyz + (size_t)gc * 3;
  const float cx = cp[0], cy = cp[1], cz = cp[2];
  const float asq = (cx * cx + cy * cy) + cz * cz;
  int cnt = 0;
  for (int base = 0; base < NPTS; base += 64) {
    int n = base + lane;
    float x = xp[n], y = xp[NPTS + n], z = xp[2 * NPTS + n];
    float bsq = (x * x + y * y) + z * z;
    float ab = (x * cx + y * cy) + z * cz;
    float sq = (asq + bsq) - 2.0f * ab;
    bool inc = !(sq > 0.01f);           // same f32 threshold as reference
    unsigned long long mk = __ballot(inc);
    int pos = cnt + (int)__popcll(mk & ((1ull << lane) - 1ull));
    if (inc && pos < NSAMPLE) slots[wv][pos] = n;
    cnt += (int)__popcll(mk);
    if (cnt >= NSAMPLE) break;          // wave-uniform
  }
  __syncthreads();
  if (lane < NSAMPLE) {
    int first = slots[wv][0];           // >=1 hit guaranteed (center itself)
    int v = (lane < cnt) ? slots[wv][lane] : first;
    idx_out[(size_t)gc * NSAMPLE + lane] = v;
  }
}

// ---------------------------------------------------------------------------
// Setup (grid = 128 blocks): every block packs 256 points of the float4
// coord table xyz4[b][n] = (x,y,z,0); block 0 additionally transposes
// w3 -> w3t and folds BN (+bias) into per-channel scale/shift.
// ---------------------------------------------------------------------------
__global__ __launch_bounds__(256) void setup_kernel(
    const float* __restrict__ xyz, const float* __restrict__ w3,
    const float* __restrict__ b1, const float* __restrict__ g1, const float* __restrict__ t1,
    const float* __restrict__ m1, const float* __restrict__ v1,
    const float* __restrict__ b2, const float* __restrict__ g2, const float* __restrict__ t2,
    const float* __restrict__ m2, const float* __restrict__ v2,
    const float* __restrict__ b3, const float* __restrict__ g3, const float* __restrict__ t3,
    const float* __restrict__ m3, const float* __restrict__ v3,
    float4* __restrict__ xyz4, float* __restrict__ w3t, float* __restrict__ scsh) {
  int tid = threadIdx.x;
  int p = blockIdx.x * 256 + tid;       // 0..32767
  int bb = p >> 13, n = p & 8191;
  const float* src = xyz + (size_t)bb * 3 * NPTS;
  xyz4[p] = make_float4(src[n], src[NPTS + n], src[2 * NPTS + n], 0.f);
  if (blockIdx.x != 0) return;
  for (int i = tid; i < 8192; i += 256) {
    int o = i >> 6, c = i & 63;
    w3t[c * 128 + o] = w3[i];
  }
  if (tid < 64) {
    float s = g1[tid] / sqrtf(v1[tid] + 1e-5f);
    scsh[tid] = s;
    scsh[64 + tid] = (b1[tid] - m1[tid]) * s + t1[tid];
    float s2 = g2[tid] / sqrtf(v2[tid] + 1e-5f);
    scsh[128 + tid] = s2;
    scsh[192 + tid] = (b2[tid] - m2[tid]) * s2 + t2[tid];
  }
  if (tid < 128) {
    float s3 = g3[tid] / sqrtf(v3[tid] + 1e-5f);
    scsh[256 + tid] = s3;
    scsh[384 + tid] = (b3[tid] - m3[tid]) * s3 + t3[tid];
  }
}

// ---------------------------------------------------------------------------
// Fused gather + MLP(6->64->64->128, BN+ReLU) + max over 32 samples.
// Block = 256 threads = 8 centers x 32 samples. Activations live in one
// 64KB LDS buffer, XOR-swizzled at float4 granularity (conflict-free at the
// b128 bank floor). L1/L2 use (center,sample) mapping (own-row, no barrier);
// L3 uses (center,channel-lane) mapping so the k-loop folds into a register
// max (no cross-lane butterfly).
// ---------------------------------------------------------------------------
__global__ __launch_bounds__(256, 2) void mlp_kernel(
    const float* __restrict__ xyz, const float* __restrict__ points,
    const float* __restrict__ new_xyz, const int* __restrict__ idx,
    const float* __restrict__ w1, const float* __restrict__ w2,
    const float* __restrict__ w3t, const float* __restrict__ scsh,
    float* __restrict__ out) {
  __shared__ float act[256 * 64];       // exactly 64 KB -> 2 blocks/CU
  float4* act4 = (float4*)act;
  const int tid = threadIdx.x;
  const int s0 = blockIdx.x * 8;
  const int b = s0 >> 10;               // 8 | 1024 -> uniform per block
  const int g = tid >> 5;               // center within block
  const int k = tid & 31;               // sample (phase A) / channel lane (L3)
  const int gc = s0 + g;
  const float* xp = xyz + (size_t)b * 3 * NPTS;
  const float* pp = points + (size_t)b * 3 * NPTS;
  const float* cp = new_xyz + (size_t)gc * 3;
  const int n = idx[(size_t)gc * NSAMPLE + k];
  float f0 = xp[n] - cp[0];
  float f1 = xp[NPTS + n] - cp[1];
  float f2 = xp[2 * NPTS + n] - cp[2];
  float f3 = pp[n];
  float f4 = pp[NPTS + n];
  float f5 = pp[2 * NPTS + n];
  const float* sc1 = scsh;        const float* sh1 = scsh + 64;
  const float* sc2 = scsh + 128;  const float* sh2 = scsh + 192;
  const float* sc3 = scsh + 256;  const float* sh3 = scsh + 384;
  const int row = tid;

  // ---- L1: x1[o] = relu(bn(W1 @ f)) -> LDS (own row, swizzled float4) ----
#pragma unroll
  for (int oc = 0; oc < 16; ++oc) {
    float va[4];
#pragma unroll
    for (int jj = 0; jj < 4; ++jj) {
      int o = oc * 4 + jj;
      const float* wr = w1 + o * 6;     // wave-uniform -> scalar loads
      float a = f0 * wr[0] + f1 * wr[1] + f2 * wr[2] +
                f3 * wr[3] + f4 * wr[4] + f5 * wr[5];
      va[jj] = fmaxf(a * sc1[o] + sh1[o], 0.f);
    }
    act4[row * 16 + (oc ^ (row & 15))] = make_float4(va[0], va[1], va[2], va[3]);
  }

  // ---- L2: own-row contraction, 64 accumulators, uniform scalar weights ----
  float acc[64];
#pragma unroll
  for (int o = 0; o < 64; ++o) acc[o] = 0.f;
  for (int cc = 0; cc < 16; ++cc) {     // dynamic: LDS handles dynamic index
    float4 av = act4[row * 16 + (cc ^ (row & 15))];
#pragma unroll
    for (int o = 0; o < 64; ++o) {
      const float* wr = w2 + o * 64 + cc * 4;  // wave-uniform address
      acc[o] += av.x * wr[0] + av.y * wr[1] + av.z * wr[2] + av.w * wr[3];
    }
  }
  // bn+relu, overwrite own row with x2 (no cross-thread x1 readers)
#pragma unroll
  for (int oc = 0; oc < 16; ++oc) {
    float va[4];
#pragma unroll
    for (int jj = 0; jj < 4; ++jj) {
      int o = oc * 4 + jj;
      va[jj] = fmaxf(acc[o] * sc2[o] + sh2[o], 0.f);
    }
    act4[row * 16 + (oc ^ (row & 15))] = make_float4(va[0], va[1], va[2], va[3]);
  }
  __syncthreads();                      // x2 visible to whole block

  // ---- L3 + max over k: lane j owns channel o3 = p*32+j ----
  const int j = k;
  const int sb = gc & 1023;
  for (int p = 0; p < 4; ++p) {
    int o3 = p * 32 + j;
    float wreg[64];
#pragma unroll
    for (int c = 0; c < 64; ++c) wreg[c] = w3t[c * 128 + o3];  // coalesced
    float osc = sc3[o3], osh = sh3[o3];
    float vmax = 0.f;                   // post-relu values are >= 0
    for (int kk = 0; kk < 32; ++kk) {
      int r2 = g * 32 + kk;             // uniform within 32-lane group
      float a0 = 0.f, a1 = 0.f, a2 = 0.f, a3 = 0.f;
#pragma unroll
      for (int cc = 0; cc < 16; cc += 4) {
        float4 u0 = act4[r2 * 16 + ((cc + 0) ^ (r2 & 15))];  // broadcast b128
        float4 u1 = act4[r2 * 16 + ((cc + 1) ^ (r2 & 15))];
        float4 u2 = act4[r2 * 16 + ((cc + 2) ^ (r2 & 15))];
        float4 u3 = act4[r2 * 16 + ((cc + 3) ^ (r2 & 15))];
        a0 += u0.x * wreg[4*cc+0]  + u0.y * wreg[4*cc+1]  + u0.z * wreg[4*cc+2]  + u0.w * wreg[4*cc+3];
        a1 += u1.x * wreg[4*cc+4]  + u1.y * wreg[4*cc+5]  + u1.z * wreg[4*cc+6]  + u1.w * wreg[4*cc+7];
        a2 += u2.x * wreg[4*cc+8]  + u2.y * wreg[4*cc+9]  + u2.z * wreg[4*cc+10] + u2.w * wreg[4*cc+11];
        a3 += u3.x * wreg[4*cc+12] + u3.y * wreg[4*cc+13] + u3.z * wreg[4*cc+14] + u3.w * wreg[4*cc+15];
      }
      float x3 = (a0 + a1) + (a2 + a3);
      vmax = fmaxf(vmax, fmaxf(x3 * osc + osh, 0.f));
    }
    out[((size_t)b * 128 + o3) * 1024 + sb] = vmax;   // (B,128,1024)
  }
}

// ---------------------------------------------------------------------------
extern "C" void kernel_launch(void* const* d_in, const int* in_sizes, int n_in,
                              void* d_out, int out_size, void* d_ws, size_t ws_size,
                              hipStream_t stream) {
  (void)in_sizes; (void)n_in; (void)out_size; (void)ws_size;
  const float* xyz    = (const float*)d_in[0];
  const float* points = (const float*)d_in[1];
  const float* w1 = (const float*)d_in[2];
  const float* b1 = (const float*)d_in[3];
  const float* g1 = (const float*)d_in[4];
  const float* t1 = (const float*)d_in[5];
  const float* m1 = (const float*)d_in[6];
  const float* v1 = (const float*)d_in[7];
  const float* w2 = (const float*)d_in[8];
  const float* b2 = (const float*)d_in[9];
  const float* g2 = (const float*)d_in[10];
  const float* t2 = (const float*)d_in[11];
  const float* m2 = (const float*)d_in[12];
  const float* v2 = (const float*)d_in[13];
  const float* w3 = (const float*)d_in[14];
  const float* b3 = (const float*)d_in[15];
  const float* g3 = (const float*)d_in[16];
  const float* t3 = (const float*)d_in[17];
  const float* m3 = (const float*)d_in[18];
  const float* v3 = (const float*)d_in[19];

  float* wsf = (float*)d_ws;
  float* new_xyz = wsf;                         // 4*1024*3   = 12288 f
  int*   idx     = (int*)(wsf + 12288);         // 4*1024*32  = 131072 i
  float* w3t     = wsf + 12288 + 131072;        // 64*128     = 8192 f
  float* scsh    = w3t + 8192;                  // 512 f
  float4* xyz4   = (float4*)(scsh + 512);       // 4*8192 float4 = 512 KB
  float* out     = (float*)d_out;               // (4,128,1024) f32

  hipLaunchKernelGGL(setup_kernel, dim3(128), dim3(256), 0, stream,
                     xyz, w3, b1, g1, t1, m1, v1, b2, g2, t2, m2, v2,
                     b3, g3, t3, m3, v3, xyz4, w3t, scsh);
  hipLaunchKernelGGL(fps_kernel, dim3(4), dim3(512), 0, stream, xyz4, new_xyz);
  hipLaunchKernelGGL(bq_kernel, dim3(1024), dim3(256), 0, stream,
                     xyz, new_xyz, idx);
  hipLaunchKernelGGL(mlp_kernel, dim3(512), dim3(256), 0, stream,
                     xyz, points, new_xyz, idx, w1, w2, w3t, scsh, out);
}

// Round 4
// 1211.720 us; speedup vs baseline: 6.1327x; 1.2323x over previous
//
#include <hip/hip_runtime.h>
#include <math.h>

#define NPTS 8192
#define NPOINT 1024
#define NSAMPLE 32

typedef float v2f __attribute__((ext_vector_type(2)));

// ---------------------------------------------------------------------------
// DPP reduce steps. bound_ctrl=true: invalid-source lanes read 0, which is
// the identity for both f32-max over values >=0 and u32-max.
// ---------------------------------------------------------------------------
template <int CTRL>
__device__ __forceinline__ float dpp_fmax_step(float v) {
  int s = __builtin_amdgcn_update_dpp(0, __float_as_int(v), CTRL, 0xF, 0xF, true);
  return fmaxf(v, __int_as_float(s));
}
template <int CTRL>
__device__ __forceinline__ unsigned dpp_umax_step(unsigned v) {
  int s = __builtin_amdgcn_update_dpp(0, (int)v, CTRL, 0xF, 0xF, true);
  unsigned u = (unsigned)s;
  return (u > v) ? u : v;
}

// ---------------------------------------------------------------------------
// FPS v10. v8/v9 post-mortem: VGPR_Count=40 with 64 floats of per-thread
// state => the allocator never kept the coords in registers; being
// rematerializable from the read-only __restrict__ table, they were
// RELOADED from global (L2) every iteration: 128 KB/iter/CU ~ 2300 cyc,
// matching the measured ~3300 cyc/iter, identical for v8 and v9 (same
// total points/CU) — which is why halving waves/SIMD changed nothing.
// v10: (a) empty asm "+v" pins make the asm the defining instruction of
// every coord v2f — no longer rematerializable, must stay in VGPRs
// (~130 regs demanded, cap 256 at 2 waves/SIMD => no spill); (b) the
// register-pressure-heavy coord-select tree and rcand are replaced by a
// float4 LDS copy of all 8192 points: after the cross-wave reduce gives
// gi, one broadcast ds_read_b128 lpts[gi] yields the centroid (same chain
// position as v9's rcand read). LDS = 128K lpts + 16K cents + 64B keys
// = 147.5 KB < 160 KB. Zero global ops in the loop, one barrier/iter.
// Bit-exact vs numpy: contract off, ((dx*dx+dy*dy)+dz*dz), min-accumulate,
// argmax first-occurrence (strict > right-wins = min index at every level;
// cross-lane/wave ties via max(8191-bi) = min global index, keys distinct).
// ---------------------------------------------------------------------------
__global__ __launch_bounds__(512, 1) void fps_kernel(const float4* __restrict__ xyz4,
                                                     float* __restrict__ new_xyz) {
#pragma clang fp contract(off)
  const int b = blockIdx.x;
  const int tid = threadIdx.x;          // 0..511
  const float4* xp4 = xyz4 + (size_t)b * NPTS;
  __shared__ float4 lpts[NPTS];                // 128 KB point copy
  __shared__ uint2 rwk[2][8];                  // per-wave {Mw bits, K2}
  __shared__ float4 cents[NPOINT];             // centroid staging (16 KB)
  // pair J holds i=2J (.x, n=tid+1024J) and i=2J+1 (.y, n=tid+1024J+512)
  v2f px0, py0, pz0, dd0;
  v2f px1, py1, pz1, dd1;
  v2f px2, py2, pz2, dd2;
  v2f px3, py3, pz3, dd3;
  v2f px4, py4, pz4, dd4;
  v2f px5, py5, pz5, dd5;
  v2f px6, py6, pz6, dd6;
  v2f px7, py7, pz7, dd7;
#define FPS_LOAD(J, PX, PY, PZ, PD)            \
  {                                            \
    float4 a = xp4[tid + 1024 * J];            \
    float4 c2 = xp4[tid + 1024 * J + 512];     \
    lpts[tid + 1024 * J] = a;                  \
    lpts[tid + 1024 * J + 512] = c2;           \
    PX = (v2f){a.x, c2.x};                     \
    PY = (v2f){a.y, c2.y};                     \
    PZ = (v2f){a.z, c2.z};                     \
    PD = (v2f){1e10f, 1e10f};                  \
  }
  FPS_LOAD(0, px0, py0, pz0, dd0)
  FPS_LOAD(1, px1, py1, pz1, dd1)
  FPS_LOAD(2, px2, py2, pz2, dd2)
  FPS_LOAD(3, px3, py3, pz3, dd3)
  FPS_LOAD(4, px4, py4, pz4, dd4)
  FPS_LOAD(5, px5, py5, pz5, dd5)
  FPS_LOAD(6, px6, py6, pz6, dd6)
  FPS_LOAD(7, px7, py7, pz7, dd7)
  // Pin the coords: the asm becomes their defining op => the register
  // allocator cannot rematerialize them via global reloads (the v8/v9 bug).
  asm volatile("" : "+v"(px0), "+v"(py0), "+v"(pz0), "+v"(px1));
  asm volatile("" : "+v"(py1), "+v"(pz1), "+v"(px2), "+v"(py2));
  asm volatile("" : "+v"(pz2), "+v"(px3), "+v"(py3), "+v"(pz3));
  asm volatile("" : "+v"(px4), "+v"(py4), "+v"(pz4), "+v"(px5));
  asm volatile("" : "+v"(py5), "+v"(pz5), "+v"(px6), "+v"(py6));
  asm volatile("" : "+v"(pz6), "+v"(px7), "+v"(py7), "+v"(pz7));
  const int wv = tid >> 6;
  const int lane = tid & 63;
  float4 c0 = xp4[0];                   // first centroid is point 0
  float cx = c0.x, cy = c0.y, cz = c0.z;
  if (tid == 0) cents[0] = make_float4(cx, cy, cz, 0.f);
  __syncthreads();                      // lpts visible before first use
  for (int s = 1; s < NPOINT; ++s) {
    const int par = s & 1;
    const v2f cxx = (v2f){cx, cx};
    const v2f cyy = (v2f){cy, cy};
    const v2f czz = (v2f){cz, cz};
    float v0, v1, v2, v3, v4, v5, v6, v7;
    int i0, i1, i2, i3, i4, i5, i6, i7;
#define FPS_DIST(J, PX, PY, PZ, PD, PV, PI)    \
  {                                            \
    v2f dx = PX - cxx;                         \
    v2f dy = PY - cyy;                         \
    v2f dz = PZ - czz;                         \
    v2f xx = dx * dx;                          \
    v2f yy = dy * dy;                          \
    v2f zz = dz * dz;                          \
    v2f d = (xx + yy) + zz;                    \
    float dmx = fminf(PD.x, d.x);              \
    float dmy = fminf(PD.y, d.y);              \
    PD.x = dmx;                                \
    PD.y = dmy;                                \
    bool c = dmy > dmx;                        \
    PV = c ? dmy : dmx;                        \
    PI = c ? (2 * J + 1) : (2 * J);            \
  }
    FPS_DIST(0, px0, py0, pz0, dd0, v0, i0)
    FPS_DIST(1, px1, py1, pz1, dd1, v1, i1)
    FPS_DIST(2, px2, py2, pz2, dd2, v2, i2)
    FPS_DIST(3, px3, py3, pz3, dd3, v3, i3)
    FPS_DIST(4, px4, py4, pz4, dd4, v4, i4)
    FPS_DIST(5, px5, py5, pz5, dd5, v5, i5)
    FPS_DIST(6, px6, py6, pz6, dd6, v6, i6)
    FPS_DIST(7, px7, py7, pz7, dd7, v7, i7)
    // 3-level argmax tree; right child wins only on strict > (min index)
    bool cA = v1 > v0;  float a0 = cA ? v1 : v0;  int j0 = cA ? i1 : i0;
    bool cB = v3 > v2;  float a1 = cB ? v3 : v2;  int j1 = cB ? i3 : i2;
    bool cC = v5 > v4;  float a2 = cC ? v5 : v4;  int j2 = cC ? i5 : i4;
    bool cD = v7 > v6;  float a3 = cD ? v7 : v6;  int j3 = cD ? i7 : i6;
    bool cE = a1 > a0;  float b0 = cE ? a1 : a0;  int k0 = cE ? j1 : j0;
    bool cF = a3 > a2;  float b1 = cF ? a3 : a2;  int k1 = cF ? j3 : j2;
    bool cG = b1 > b0;
    const float bv = cG ? b1 : b0;
    const int bI = cG ? k1 : k0;        // 0..15
    const int bi = tid + (bI << 9);     // global point index (n = tid+512*i)
    // --- wave reduce, phase 1: max value (bv >= 0, f32 max) ---
    float m = bv;
    m = dpp_fmax_step<0x111>(m);        // row_shr:1
    m = dpp_fmax_step<0x112>(m);        // row_shr:2
    m = dpp_fmax_step<0x114>(m);        // row_shr:4
    m = dpp_fmax_step<0x118>(m);        // row_shr:8
    m = dpp_fmax_step<0x142>(m);        // row_bcast:15
    m = dpp_fmax_step<0x143>(m);        // row_bcast:31
    float Mw = __int_as_float(__builtin_amdgcn_readlane(__float_as_int(m), 63));
    // --- phase 2: among lanes at the max, min index via max(8191-bi) ---
    unsigned kc = (bv == Mw) ? (unsigned)(8191 - bi) : 0u;
    kc = dpp_umax_step<0x111>(kc);
    kc = dpp_umax_step<0x112>(kc);
    kc = dpp_umax_step<0x114>(kc);
    kc = dpp_umax_step<0x118>(kc);
    kc = dpp_umax_step<0x142>(kc);
    kc = dpp_umax_step<0x143>(kc);
    unsigned K2 = (unsigned)__builtin_amdgcn_readlane((int)kc, 63);
    // exactly one lane per wave matches (bi unique across the block)
    if (bv == Mw && (unsigned)(8191 - bi) == K2) {
      rwk[par][wv] = make_uint2(__float_as_uint(Mw), K2);
    }
    __syncthreads();                    // the only barrier per iteration
    // --- slim cross-wave reduce: lane-parallel over the 8 wave results ---
    uint2 wk = rwk[par][lane & 7];      // 8-way broadcast ds_read_b64
    float mw = __uint_as_float(wk.x);
    float mm = mw;
    mm = dpp_fmax_step<0x111>(mm);      // row_shr:1 (within row of 16)
    mm = dpp_fmax_step<0x112>(mm);      // row_shr:2
    mm = dpp_fmax_step<0x114>(mm);      // row_shr:4 -> lane 7 = max(l0..l7)
    float Mv = __int_as_float(__builtin_amdgcn_readlane(__float_as_int(mm), 7));
    unsigned kx = (mw == Mv) ? wk.y : 0u;
    kx = dpp_umax_step<0x111>(kx);
    kx = dpp_umax_step<0x112>(kx);
    kx = dpp_umax_step<0x114>(kx);
    unsigned K = (unsigned)__builtin_amdgcn_readlane((int)kx, 7);
    const int gi = 8191 - (int)K;
    float4 cc = lpts[gi];               // broadcast ds_read_b128 (uniform)
    cx = cc.x;
    cy = cc.y;
    cz = cc.z;
    if (tid == 0) cents[s] = make_float4(cx, cy, cz, 0.f);
  }
  __syncthreads();
  // coalesced one-shot dump of the 1024 centroids (12 KB)
  float* outp = new_xyz + (size_t)b * NPOINT * 3;
  for (int t = tid; t < 3 * NPOINT; t += 512) {
    int sI = t / 3;
    int cI = t - 3 * sI;
    const float* cf = (const float*)&cents[sI];
    outp[t] = cf[cI];
  }
}

// ---------------------------------------------------------------------------
// Ball query: one wave per center. Replicates the reference's expanded
// sq = |a|^2 + |b|^2 - 2 a.b (contract off) and first-32-by-index semantics.
// ---------------------------------------------------------------------------
__global__ __launch_bounds__(256) void bq_kernel(const float* __restrict__ xyz,
                                                 const float* __restrict__ new_xyz,
                                                 int* __restrict__ idx_out) {
#pragma clang fp contract(off)
  __shared__ int slots[4][NSAMPLE];
  const int tid = threadIdx.x;
  const int wv = tid >> 6, lane = tid & 63;
  const int gc = blockIdx.x * 4 + wv;   // global center 0..4095
  const int b = gc >> 10;
  const float* xp = xyz + (size_t)b * 3 * NPTS;
  const float* cp = new_xyz + (size_t)gc * 3;
  const float cx = cp[0], cy = cp[1], cz = cp[2];
  const float asq = (cx * cx + cy * cy) + cz * cz;
  int cnt = 0;
  for (int base = 0; base < NPTS; base += 64) {
    int n = base + lane;
    float x = xp[n], y = xp[NPTS + n], z = xp[2 * NPTS + n];
    float bsq = (x * x + y * y) + z * z;
    float ab = (x * cx + y * cy) + z * cz;
    float sq = (asq + bsq) - 2.0f * ab;
    bool inc = !(sq > 0.01f);           // same f32 threshold as reference
    unsigned long long mk = __ballot(inc);
    int pos = cnt + (int)__popcll(mk & ((1ull << lane) - 1ull));
    if (inc && pos < NSAMPLE) slots[wv][pos] = n;
    cnt += (int)__popcll(mk);
    if (cnt >= NSAMPLE) break;          // wave-uniform
  }
  __syncthreads();
  if (lane < NSAMPLE) {
    int first = slots[wv][0];           // >=1 hit guaranteed (center itself)
    int v = (lane < cnt) ? slots[wv][lane] : first;
    idx_out[(size_t)gc * NSAMPLE + lane] = v;
  }
}

// ---------------------------------------------------------------------------
// Setup (grid = 128 blocks): every block packs 256 points of the float4
// coord table xyz4[b][n] = (x,y,z,0); block 0 additionally transposes
// w3 -> w3t and folds BN (+bias) into per-channel scale/shift.
// ---------------------------------------------------------------------------
__global__ __launch_bounds__(256) void setup_kernel(
    const float* __restrict__ xyz, const float* __restrict__ w3,
    const float* __restrict__ b1, const float* __restrict__ g1, const float* __restrict__ t1,
    const float* __restrict__ m1, const float* __restrict__ v1,
    const float* __restrict__ b2, const float* __restrict__ g2, const float* __restrict__ t2,
    const float* __restrict__ m2, const float* __restrict__ v2,
    const float* __restrict__ b3, const float* __restrict__ g3, const float* __restrict__ t3,
    const float* __restrict__ m3, const float* __restrict__ v3,
    float4* __restrict__ xyz4, float* __restrict__ w3t, float* __restrict__ scsh) {
  int tid = threadIdx.x;
  int p = blockIdx.x * 256 + tid;       // 0..32767
  int bb = p >> 13, n = p & 8191;
  const float* src = xyz + (size_t)bb * 3 * NPTS;
  xyz4[p] = make_float4(src[n], src[NPTS + n], src[2 * NPTS + n], 0.f);
  if (blockIdx.x != 0) return;
  for (int i = tid; i < 8192; i += 256) {
    int o = i >> 6, c = i & 63;
    w3t[c * 128 + o] = w3[i];
  }
  if (tid < 64) {
    float s = g1[tid] / sqrtf(v1[tid] + 1e-5f);
    scsh[tid] = s;
    scsh[64 + tid] = (b1[tid] - m1[tid]) * s + t1[tid];
    float s2 = g2[tid] / sqrtf(v2[tid] + 1e-5f);
    scsh[128 + tid] = s2;
    scsh[192 + tid] = (b2[tid] - m2[tid]) * s2 + t2[tid];
  }
  if (tid < 128) {
    float s3 = g3[tid] / sqrtf(v3[tid] + 1e-5f);
    scsh[256 + tid] = s3;
    scsh[384 + tid] = (b3[tid] - m3[tid]) * s3 + t3[tid];
  }
}

// ---------------------------------------------------------------------------
// Fused gather + MLP(6->64->64->128, BN+ReLU) + max over 32 samples.
// Block = 256 threads = 8 centers x 32 samples. Activations live in one
// 64KB LDS buffer, XOR-swizzled at float4 granularity (conflict-free at the
// b128 bank floor). L1/L2 use (center,sample) mapping (own-row, no barrier);
// L3 uses (center,channel-lane) mapping so the k-loop folds into a register
// max (no cross-lane butterfly).
// ---------------------------------------------------------------------------
__global__ __launch_bounds__(256, 2) void mlp_kernel(
    const float* __restrict__ xyz, const float* __restrict__ points,
    const float* __restrict__ new_xyz, const int* __restrict__ idx,
    const float* __restrict__ w1, const float* __restrict__ w2,
    const float* __restrict__ w3t, const float* __restrict__ scsh,
    float* __restrict__ out) {
  __shared__ float act[256 * 64];       // exactly 64 KB -> 2 blocks/CU
  float4* act4 = (float4*)act;
  const int tid = threadIdx.x;
  const int s0 = blockIdx.x * 8;
  const int b = s0 >> 10;               // 8 | 1024 -> uniform per block
  const int g = tid >> 5;               // center within block
  const int k = tid & 31;               // sample (phase A) / channel lane (L3)
  const int gc = s0 + g;
  const float* xp = xyz + (size_t)b * 3 * NPTS;
  const float* pp = points + (size_t)b * 3 * NPTS;
  const float* cp = new_xyz + (size_t)gc * 3;
  const int n = idx[(size_t)gc * NSAMPLE + k];
  float f0 = xp[n] - cp[0];
  float f1 = xp[NPTS + n] - cp[1];
  float f2 = xp[2 * NPTS + n] - cp[2];
  float f3 = pp[n];
  float f4 = pp[NPTS + n];
  float f5 = pp[2 * NPTS + n];
  const float* sc1 = scsh;        const float* sh1 = scsh + 64;
  const float* sc2 = scsh + 128;  const float* sh2 = scsh + 192;
  const float* sc3 = scsh + 256;  const float* sh3 = scsh + 384;
  const int row = tid;

  // ---- L1: x1[o] = relu(bn(W1 @ f)) -> LDS (own row, swizzled float4) ----
#pragma unroll
  for (int oc = 0; oc < 16; ++oc) {
    float va[4];
#pragma unroll
    for (int jj = 0; jj < 4; ++jj) {
      int o = oc * 4 + jj;
      const float* wr = w1 + o * 6;     // wave-uniform -> scalar loads
      float a = f0 * wr[0] + f1 * wr[1] + f2 * wr[2] +
                f3 * wr[3] + f4 * wr[4] + f5 * wr[5];
      va[jj] = fmaxf(a * sc1[o] + sh1[o], 0.f);
    }
    act4[row * 16 + (oc ^ (row & 15))] = make_float4(va[0], va[1], va[2], va[3]);
  }

  // ---- L2: own-row contraction, 64 accumulators, uniform scalar weights ----
  float acc[64];
#pragma unroll
  for (int o = 0; o < 64; ++o) acc[o] = 0.f;
  for (int cc = 0; cc < 16; ++cc) {     // dynamic: LDS handles dynamic index
    float4 av = act4[row * 16 + (cc ^ (row & 15))];
#pragma unroll
    for (int o = 0; o < 64; ++o) {
      const float* wr = w2 + o * 64 + cc * 4;  // wave-uniform address
      acc[o] += av.x * wr[0] + av.y * wr[1] + av.z * wr[2] + av.w * wr[3];
    }
  }
  // bn+relu, overwrite own row with x2 (no cross-thread x1 readers)
#pragma unroll
  for (int oc = 0; oc < 16; ++oc) {
    float va[4];
#pragma unroll
    for (int jj = 0; jj < 4; ++jj) {
      int o = oc * 4 + jj;
      va[jj] = fmaxf(acc[o] * sc2[o] + sh2[o], 0.f);
    }
    act4[row * 16 + (oc ^ (row & 15))] = make_float4(va[0], va[1], va[2], va[3]);
  }
  __syncthreads();                      // x2 visible to whole block

  // ---- L3 + max over k: lane j owns channel o3 = p*32+j ----
  const int j = k;
  const int sb = gc & 1023;
  for (int p = 0; p < 4; ++p) {
    int o3 = p * 32 + j;
    float wreg[64];
#pragma unroll
    for (int c = 0; c < 64; ++c) wreg[c] = w3t[c * 128 + o3];  // coalesced
    float osc = sc3[o3], osh = sh3[o3];
    float vmax = 0.f;                   // post-relu values are >= 0
    for (int kk = 0; kk < 32; ++kk) {
      int r2 = g * 32 + kk;             // uniform within 32-lane group
      float a0 = 0.f, a1 = 0.f, a2 = 0.f, a3 = 0.f;
#pragma unroll
      for (int cc = 0; cc < 16; cc += 4) {
        float4 u0 = act4[r2 * 16 + ((cc + 0) ^ (r2 & 15))];  // broadcast b128
        float4 u1 = act4[r2 * 16 + ((cc + 1) ^ (r2 & 15))];
        float4 u2 = act4[r2 * 16 + ((cc + 2) ^ (r2 & 15))];
        float4 u3 = act4[r2 * 16 + ((cc + 3) ^ (r2 & 15))];
        a0 += u0.x * wreg[4*cc+0]  + u0.y * wreg[4*cc+1]  + u0.z * wreg[4*cc+2]  + u0.w * wreg[4*cc+3];
        a1 += u1.x * wreg[4*cc+4]  + u1.y * wreg[4*cc+5]  + u1.z * wreg[4*cc+6]  + u1.w * wreg[4*cc+7];
        a2 += u2.x * wreg[4*cc+8]  + u2.y * wreg[4*cc+9]  + u2.z * wreg[4*cc+10] + u2.w * wreg[4*cc+11];
        a3 += u3.x * wreg[4*cc+12] + u3.y * wreg[4*cc+13] + u3.z * wreg[4*cc+14] + u3.w * wreg[4*cc+15];
      }
      float x3 = (a0 + a1) + (a2 + a3);
      vmax = fmaxf(vmax, fmaxf(x3 * osc + osh, 0.f));
    }
    out[((size_t)b * 128 + o3) * 1024 + sb] = vmax;   // (B,128,1024)
  }
}

// ---------------------------------------------------------------------------
extern "C" void kernel_launch(void* const* d_in, const int* in_sizes, int n_in,
                              void* d_out, int out_size, void* d_ws, size_t ws_size,
                              hipStream_t stream) {
  (void)in_sizes; (void)n_in; (void)out_size; (void)ws_size;
  const float* xyz    = (const float*)d_in[0];
  const float* points = (const float*)d_in[1];
  const float* w1 = (const float*)d_in[2];
  const float* b1 = (const float*)d_in[3];
  const float* g1 = (const float*)d_in[4];
  const float* t1 = (const float*)d_in[5];
  const float* m1 = (const float*)d_in[6];
  const float* v1 = (const float*)d_in[7];
  const float* w2 = (const float*)d_in[8];
  const float* b2 = (const float*)d_in[9];
  const float* g2 = (const float*)d_in[10];
  const float* t2 = (const float*)d_in[11];
  const float* m2 = (const float*)d_in[12];
  const float* v2 = (const float*)d_in[13];
  const float* w3 = (const float*)d_in[14];
  const float* b3 = (const float*)d_in[15];
  const float* g3 = (const float*)d_in[16];
  const float* t3 = (const float*)d_in[17];
  const float* m3 = (const float*)d_in[18];
  const float* v3 = (const float*)d_in[19];

  float* wsf = (float*)d_ws;
  float* new_xyz = wsf;                         // 4*1024*3   = 12288 f
  int*   idx     = (int*)(wsf + 12288);         // 4*1024*32  = 131072 i
  float* w3t     = wsf + 12288 + 131072;        // 64*128     = 8192 f
  float* scsh    = w3t + 8192;                  // 512 f
  float4* xyz4   = (float4*)(scsh + 512);       // 4*8192 float4 = 512 KB
  float* out     = (float*)d_out;               // (4,128,1024) f32

  hipLaunchKernelGGL(setup_kernel, dim3(128), dim3(256), 0, stream,
                     xyz, w3, b1, g1, t1, m1, v1, b2, g2, t2, m2, v2,
                     b3, g3, t3, m3, v3, xyz4, w3t, scsh);
  hipLaunchKernelGGL(fps_kernel, dim3(4), dim3(512), 0, stream, xyz4, new_xyz);
  hipLaunchKernelGGL(bq_kernel, dim3(1024), dim3(256), 0, stream,
                     xyz, new_xyz, idx);
  hipLaunchKernelGGL(mlp_kernel, dim3(512), dim3(256), 0, stream,
                     xyz, points, new_xyz, idx, w1, w2, w3t, scsh, out);
}